// Round 2
// baseline (778.340 us; speedup 1.0000x reference)
//
#include <hip/hip_runtime.h>

typedef unsigned short u16;
typedef __attribute__((ext_vector_type(8))) unsigned short u16x8;
typedef __attribute__((ext_vector_type(8))) __bf16 bf16x8;
typedef __attribute__((ext_vector_type(4))) float f32x4;

#define DEV __device__ __forceinline__

DEV u16 f2bf(float f) {
  unsigned u = __builtin_bit_cast(unsigned, f);
  u += 0x7FFFu + ((u >> 16) & 1u);
  return (u16)(u >> 16);
}
DEV float bf2f(u16 h) {
  unsigned u = ((unsigned)h) << 16;
  return __builtin_bit_cast(float, u);
}
DEV f32x4 mfma16(u16x8 a, u16x8 b, f32x4 c) {
  return __builtin_amdgcn_mfma_f32_16x16x32_bf16(
      __builtin_bit_cast(bf16x8, a), __builtin_bit_cast(bf16x8, b), c, 0, 0, 0);
}
DEV void gload_lds16(const void* g, void* l) {
  __builtin_amdgcn_global_load_lds(
      (const __attribute__((address_space(1))) void*)g,
      (__attribute__((address_space(3))) void*)l, 16, 0, 0);
}

// ---------------- weight cast fp32 -> bf16 ----------------
__global__ __launch_bounds__(256) void cast_w(const float* __restrict__ in, u16* __restrict__ out) {
  size_t i = ((size_t)blockIdx.x * 256 + threadIdx.x) * 8;
  float4 a = *(const float4*)(in + i);
  float4 b = *(const float4*)(in + i + 4);
  u16x8 o;
  o[0] = f2bf(a.x); o[1] = f2bf(a.y); o[2] = f2bf(a.z); o[3] = f2bf(a.w);
  o[4] = f2bf(b.x); o[5] = f2bf(b.y); o[6] = f2bf(b.z); o[7] = f2bf(b.w);
  *(u16x8*)(out + i) = o;
}

// ---------------- RMSNorm (fp32 in) -> bf16 out ----------------
__global__ __launch_bounds__(256) void rmsnorm_cast(const float* __restrict__ x, const float* __restrict__ w,
                                                    u16* __restrict__ out) {
  const int row = blockIdx.x, tid = threadIdx.x;
  const float* xr = x + (size_t)row * 2048;
  float4 a = *(const float4*)(xr + tid * 8);
  float4 b = *(const float4*)(xr + tid * 8 + 4);
  float ss = a.x * a.x + a.y * a.y + a.z * a.z + a.w * a.w +
             b.x * b.x + b.y * b.y + b.z * b.z + b.w * b.w;
#pragma unroll
  for (int off = 32; off; off >>= 1) ss += __shfl_xor(ss, off);
  __shared__ float part[4];
  if ((tid & 63) == 0) part[tid >> 6] = ss;
  __syncthreads();
  float tot = part[0] + part[1] + part[2] + part[3];
  float r = rsqrtf(tot * (1.0f / 2048.0f) + 1e-5f);
  float4 wa = *(const float4*)(w + tid * 8);
  float4 wb = *(const float4*)(w + tid * 8 + 4);
  u16x8 o;
  o[0] = f2bf(a.x * r * wa.x); o[1] = f2bf(a.y * r * wa.y);
  o[2] = f2bf(a.z * r * wa.z); o[3] = f2bf(a.w * r * wa.w);
  o[4] = f2bf(b.x * r * wb.x); o[5] = f2bf(b.y * r * wb.y);
  o[6] = f2bf(b.z * r * wb.z); o[7] = f2bf(b.w * r * wb.w);
  *(u16x8*)(out + (size_t)row * 2048 + tid * 8) = o;
}

// ---------------- NT GEMM: C[m,n] = dot(A[m,:K], B[n,:K]) ----------------
// EPI 0: out bf16 (+ batch z). EPI 1: out fp32 = acc + extra(fp32). EPI 2: out bf16 = extra(bf16)*silu(acc).
template <int EPI>
__global__ __launch_bounds__(256) void gemm_bt(const u16* __restrict__ A, const u16* __restrict__ B,
                                               void* __restrict__ outp, const void* __restrict__ extra,
                                               int M, int N, int K, long long bStrideB, long long bStrideO) {
  __shared__ u16 As[128 * 32];
  __shared__ u16 Bs[128 * 32];
  const u16* Bp = B + (size_t)blockIdx.z * bStrideB;
  const int bm = blockIdx.y * 128, bn = blockIdx.x * 128;
  const int w = threadIdx.x >> 6, l = threadIdx.x & 63;
  const int l16 = l & 15, l4 = l >> 4;
  const int wm = (w >> 1) * 64, wn = (w & 1) * 64;
  const int srow = l >> 2, scol = (l & 3) * 8;
  f32x4 acc[4][4] = {};
  for (int kt = 0; kt < K; kt += 32) {
#pragma unroll
    for (int i = 0; i < 2; ++i) {
      const int rb = (w * 2 + i) * 16;
      gload_lds16(A + (size_t)(bm + rb + srow) * K + kt + scol, &As[rb * 32]);
      gload_lds16(Bp + (size_t)(bn + rb + srow) * K + kt + scol, &Bs[rb * 32]);
    }
    __syncthreads();
    u16x8 af[4], bfr[4];
#pragma unroll
    for (int mt = 0; mt < 4; ++mt) af[mt] = *(const u16x8*)&As[(wm + mt * 16 + l16) * 32 + l4 * 8];
#pragma unroll
    for (int nt = 0; nt < 4; ++nt) bfr[nt] = *(const u16x8*)&Bs[(wn + nt * 16 + l16) * 32 + l4 * 8];
#pragma unroll
    for (int mt = 0; mt < 4; ++mt)
#pragma unroll
      for (int nt = 0; nt < 4; ++nt)
        acc[mt][nt] = mfma16(af[mt], bfr[nt], acc[mt][nt]);
    __syncthreads();
  }
#pragma unroll
  for (int mt = 0; mt < 4; ++mt)
#pragma unroll
    for (int nt = 0; nt < 4; ++nt)
#pragma unroll
      for (int r = 0; r < 4; ++r) {
        const int row = bm + wm + mt * 16 + l4 * 4 + r;
        const int col = bn + wn + nt * 16 + l16;
        const size_t idx = (size_t)row * N + col;
        float v = acc[mt][nt][r];
        if (EPI == 0) {
          ((u16*)outp)[(size_t)blockIdx.z * bStrideO + idx] = f2bf(v);
        } else if (EPI == 1) {
          ((float*)outp)[idx] = v + ((const float*)extra)[idx];
        } else {
          float g = bf2f(((const u16*)extra)[idx]);
          float sig = 1.0f / (1.0f + __expf(-v));
          ((u16*)outp)[idx] = f2bf(g * v * sig);
        }
      }
}

// ---------------- RoPE ----------------
__global__ __launch_bounds__(256) void rope_table(float2* __restrict__ tab) {
  int idx = blockIdx.x * 256 + threadIdx.x;  // S*32 = 65536
  int pos = idx >> 5, i = idx & 31;
  // inv_freq = 10000^(-2i/64) = exp(-2i/64 * ln(10000))
  float inv = __expf(-(float)(2 * i) * (9.210340371976184f / 64.0f));
  float a = (float)pos * inv;
  float s, c;
  __sincosf(a, &s, &c);
  tab[idx] = make_float2(c, s);
}

__global__ __launch_bounds__(256) void rope_apply(u16* __restrict__ q, u16* __restrict__ k,
                                                  const float2* __restrict__ tab) {
  int idx = blockIdx.x * 256 + threadIdx.x;  // S*H*32 = 2M
  int i = idx & 31;
  int hh = (idx >> 5) & 31;
  int pos = idx >> 10;
  float2 cs = tab[(pos << 5) + i];
  size_t base = (size_t)pos * 2048 + hh * 64 + i;
  float a0 = bf2f(q[base]), a1 = bf2f(q[base + 32]);
  q[base] = f2bf(a0 * cs.x - a1 * cs.y);
  q[base + 32] = f2bf(a1 * cs.x + a0 * cs.y);
  float b0 = bf2f(k[base]), b1 = bf2f(k[base + 32]);
  k[base] = f2bf(b0 * cs.x - b1 * cs.y);
  k[base + 32] = f2bf(b1 * cs.x + b0 * cs.y);
}

// ---------------- V transpose: v[S][D] -> vT[h][d][S] ----------------
__global__ __launch_bounds__(256) void transpose_v(const u16* __restrict__ v, u16* __restrict__ vt) {
  __shared__ u16 t[64][72];
  const int t0 = blockIdx.x * 64, h = blockIdx.y, tid = threadIdx.x;
  {
    const int r = tid >> 3, c8 = (tid & 7) * 8;
#pragma unroll
    for (int j = 0; j < 2; ++j) {
      u16x8 val = *(const u16x8*)(v + (size_t)(t0 + r + 32 * j) * 2048 + h * 64 + c8);
      *(u16x8*)&t[r + 32 * j][c8] = val;
    }
  }
  __syncthreads();
  const int d = tid >> 2, q = (tid & 3) * 16;
  u16x8 lo, hi;
#pragma unroll
  for (int e = 0; e < 8; ++e) lo[e] = t[q + e][d];
#pragma unroll
  for (int e = 0; e < 8; ++e) hi[e] = t[q + 8 + e][d];
  *(u16x8*)(vt + (size_t)(h * 64 + d) * 2048 + t0 + q) = lo;
  *(u16x8*)(vt + (size_t)(h * 64 + d) * 2048 + t0 + q + 8) = hi;
}

// ---------------- Flash attention ----------------
// grid (S/128, H), 256 threads = 4 waves, each wave: 32 q-rows.
__global__ __launch_bounds__(256) void flash_attn(const u16* __restrict__ qb, const u16* __restrict__ kb,
                                                  const u16* __restrict__ vt, u16* __restrict__ ob) {
  const int h = blockIdx.y;
  const int q0 = blockIdx.x * 128;
  const int w = threadIdx.x >> 6, l = threadIdx.x & 63;
  const int l16 = l & 15, l4 = l >> 4;
  __shared__ u16 P[4][32][72];
  u16x8 qf[2][2];
#pragma unroll
  for (int rt = 0; rt < 2; ++rt)
#pragma unroll
    for (int kh = 0; kh < 2; ++kh)
      qf[rt][kh] = *(const u16x8*)(qb + (size_t)(q0 + w * 32 + rt * 16 + l16) * 2048 + h * 64 + kh * 32 + l4 * 8);
  float mrun[2][4], lrun[2][4];
  f32x4 oacc[2][4] = {};
#pragma unroll
  for (int rt = 0; rt < 2; ++rt)
#pragma unroll
    for (int r = 0; r < 4; ++r) { mrun[rt][r] = -1e30f; lrun[rt][r] = 0.f; }

  for (int t0 = 0; t0 < 2048; t0 += 64) {
    u16x8 kf[4][2];
#pragma unroll
    for (int tt = 0; tt < 4; ++tt)
#pragma unroll
      for (int kh = 0; kh < 2; ++kh)
        kf[tt][kh] = *(const u16x8*)(kb + (size_t)(t0 + tt * 16 + l16) * 2048 + h * 64 + kh * 32 + l4 * 8);
    f32x4 sacc[2][4] = {};
#pragma unroll
    for (int kh = 0; kh < 2; ++kh)
#pragma unroll
      for (int rt = 0; rt < 2; ++rt)
#pragma unroll
        for (int tt = 0; tt < 4; ++tt)
          sacc[rt][tt] = mfma16(qf[rt][kh], kf[tt][kh], sacc[rt][tt]);
    float sf[2][4];
#pragma unroll
    for (int rt = 0; rt < 2; ++rt)
#pragma unroll
      for (int r = 0; r < 4; ++r) {
        float v0 = sacc[rt][0][r] * 0.125f;
        float v1 = sacc[rt][1][r] * 0.125f;
        float v2 = sacc[rt][2][r] * 0.125f;
        float v3 = sacc[rt][3][r] * 0.125f;
        float mx = fmaxf(fmaxf(v0, v1), fmaxf(v2, v3));
        mx = fmaxf(mx, __shfl_xor(mx, 1));
        mx = fmaxf(mx, __shfl_xor(mx, 2));
        mx = fmaxf(mx, __shfl_xor(mx, 4));
        mx = fmaxf(mx, __shfl_xor(mx, 8));
        float mnew = fmaxf(mrun[rt][r], mx);
        float sfac = __expf(mrun[rt][r] - mnew);
        float p0 = __expf(v0 - mnew), p1 = __expf(v1 - mnew);
        float p2 = __expf(v2 - mnew), p3 = __expf(v3 - mnew);
        const int pr = rt * 16 + l4 * 4 + r;
        P[w][pr][l16] = f2bf(p0);
        P[w][pr][16 + l16] = f2bf(p1);
        P[w][pr][32 + l16] = f2bf(p2);
        P[w][pr][48 + l16] = f2bf(p3);
        float ps = p0 + p1 + p2 + p3;
        ps += __shfl_xor(ps, 1);
        ps += __shfl_xor(ps, 2);
        ps += __shfl_xor(ps, 4);
        ps += __shfl_xor(ps, 8);
        lrun[rt][r] = lrun[rt][r] * sfac + ps;
        mrun[rt][r] = mnew;
        sf[rt][r] = sfac;
      }
#pragma unroll
    for (int rt = 0; rt < 2; ++rt)
#pragma unroll
      for (int nt = 0; nt < 4; ++nt)
#pragma unroll
        for (int r = 0; r < 4; ++r)
          oacc[rt][nt][r] *= sf[rt][r];
#pragma unroll
    for (int ks = 0; ks < 2; ++ks) {
      u16x8 pf[2];
#pragma unroll
      for (int rt = 0; rt < 2; ++rt)
        pf[rt] = *(const u16x8*)&P[w][rt * 16 + l16][ks * 32 + l4 * 8];
#pragma unroll
      for (int nt = 0; nt < 4; ++nt) {
        u16x8 vf = *(const u16x8*)(vt + (size_t)(h * 64 + nt * 16 + l16) * 2048 + t0 + ks * 32 + l4 * 8);
#pragma unroll
        for (int rt = 0; rt < 2; ++rt)
          oacc[rt][nt] = mfma16(pf[rt], vf, oacc[rt][nt]);
      }
    }
  }
#pragma unroll
  for (int rt = 0; rt < 2; ++rt)
#pragma unroll
    for (int r = 0; r < 4; ++r) {
      float inv = 1.0f / lrun[rt][r];
#pragma unroll
      for (int nt = 0; nt < 4; ++nt)
        ob[(size_t)(q0 + w * 32 + rt * 16 + l4 * 4 + r) * 2048 + h * 64 + nt * 16 + l16] =
            f2bf(oacc[rt][nt][r] * inv);
    }
}

extern "C" void kernel_launch(void* const* d_in, const int* in_sizes, int n_in,
                              void* d_out, int out_size, void* d_ws, size_t ws_size,
                              hipStream_t stream) {
  const float* x    = (const float*)d_in[0];
  const float* w_in = (const float*)d_in[1];
  const float* wq   = (const float*)d_in[2];
  const float* wk   = (const float*)d_in[3];
  const float* wv   = (const float*)d_in[4];
  const float* wo   = (const float*)d_in[5];
  const float* w_pn = (const float*)d_in[6];
  const float* wg   = (const float*)d_in[7];
  const float* wu   = (const float*)d_in[8];
  const float* wd   = (const float*)d_in[9];
  float* out = (float*)d_out;
  char* ws = (char*)d_ws;
  const size_t MB = 1ull << 20;
  const int S = 2048, D = 2048, FF = 8192;

  u16* W_QKV = (u16*)(ws);             // 24 MB
  u16* W_O   = (u16*)(ws + 24 * MB);   // 8 MB
  u16* W_G   = (u16*)(ws + 32 * MB);   // 32 MB
  u16* W_U   = (u16*)(ws + 64 * MB);   // 32 MB
  u16* W_D   = (u16*)(ws + 96 * MB);   // 32 MB
  u16* HB    = (u16*)(ws + 128 * MB);  // 8 MB
  u16* QKVB  = (u16*)(ws + 136 * MB);  // 24 MB (q,k,v)
  u16* VT    = (u16*)(ws + 160 * MB);  // 8 MB
  u16* ATTNB = (u16*)(ws + 168 * MB);  // 8 MB
  float* X1  = (float*)(ws + 176 * MB);  // 16 MB
  u16* H2B   = (u16*)(ws + 192 * MB);  // 8 MB
  float2* RT = (float2*)(ws + 200 * MB);  // 0.5 MB
  u16* GATEB = (u16*)(ws);             // 32 MB, overlays W_QKV+W_O (dead after O-proj)
  u16* PRODB = (u16*)(ws + 136 * MB);  // 32 MB, overlays QKVB+VT (dead after attention)

  rope_table<<<65536 / 256, 256, 0, stream>>>(RT);
  cast_w<<<(D * D) / 2048, 256, 0, stream>>>(wq, W_QKV);
  cast_w<<<(D * D) / 2048, 256, 0, stream>>>(wk, W_QKV + (size_t)D * D);
  cast_w<<<(D * D) / 2048, 256, 0, stream>>>(wv, W_QKV + 2 * (size_t)D * D);
  cast_w<<<(D * D) / 2048, 256, 0, stream>>>(wo, W_O);
  cast_w<<<(FF * D) / 2048, 256, 0, stream>>>(wg, W_G);
  cast_w<<<(FF * D) / 2048, 256, 0, stream>>>(wu, W_U);
  cast_w<<<(FF * D) / 2048, 256, 0, stream>>>(wd, W_D);
  rmsnorm_cast<<<S, 256, 0, stream>>>(x, w_in, HB);
  gemm_bt<0><<<dim3(D / 128, S / 128, 3), 256, 0, stream>>>(HB, W_QKV, QKVB, nullptr, S, D, D,
                                                            (long long)D * D, (long long)S * D);
  rope_apply<<<(S * 32 * 32) / 256, 256, 0, stream>>>(QKVB, QKVB + (size_t)S * D, RT);
  transpose_v<<<dim3(S / 64, 32), 256, 0, stream>>>(QKVB + 2 * (size_t)S * D, VT);
  flash_attn<<<dim3(S / 128, 32), 256, 0, stream>>>(QKVB, QKVB + (size_t)S * D, VT, ATTNB);
  gemm_bt<1><<<dim3(D / 128, S / 128, 1), 256, 0, stream>>>(ATTNB, W_O, X1, x, S, D, D, 0, 0);
  rmsnorm_cast<<<S, 256, 0, stream>>>(X1, w_pn, H2B);
  gemm_bt<0><<<dim3(FF / 128, S / 128, 1), 256, 0, stream>>>(H2B, W_G, GATEB, nullptr, S, FF, D, 0, 0);
  gemm_bt<2><<<dim3(FF / 128, S / 128, 1), 256, 0, stream>>>(H2B, W_U, PRODB, GATEB, S, FF, D, 0, 0);
  gemm_bt<1><<<dim3(D / 128, S / 128, 1), 256, 0, stream>>>(PRODB, W_D, out, X1, S, D, FF, 0, 0);
  (void)in_sizes; (void)n_in; (void)out_size; (void)ws_size;
}

// Round 3
// 613.745 us; speedup vs baseline: 1.2682x; 1.2682x over previous
//
#include <hip/hip_runtime.h>

typedef unsigned short u16;
typedef __attribute__((ext_vector_type(8))) unsigned short u16x8;
typedef __attribute__((ext_vector_type(8))) __bf16 bf16x8;
typedef __attribute__((ext_vector_type(4))) float f32x4;

#define DEV __device__ __forceinline__

DEV u16 f2bf(float f) {
  unsigned u = __builtin_bit_cast(unsigned, f);
  u += 0x7FFFu + ((u >> 16) & 1u);
  return (u16)(u >> 16);
}
DEV float bf2f(u16 h) {
  unsigned u = ((unsigned)h) << 16;
  return __builtin_bit_cast(float, u);
}
DEV f32x4 mfma16(u16x8 a, u16x8 b, f32x4 c) {
  return __builtin_amdgcn_mfma_f32_16x16x32_bf16(
      __builtin_bit_cast(bf16x8, a), __builtin_bit_cast(bf16x8, b), c, 0, 0, 0);
}
DEV void gload_lds16(const void* g, void* l) {
  __builtin_amdgcn_global_load_lds(
      (const __attribute__((address_space(1))) void*)g,
      (__attribute__((address_space(3))) void*)l, 16, 0, 0);
}

// ---------------- weight cast fp32 -> bf16 ----------------
__global__ __launch_bounds__(256) void cast_w(const float* __restrict__ in, u16* __restrict__ out) {
  size_t i = ((size_t)blockIdx.x * 256 + threadIdx.x) * 8;
  float4 a = *(const float4*)(in + i);
  float4 b = *(const float4*)(in + i + 4);
  u16x8 o;
  o[0] = f2bf(a.x); o[1] = f2bf(a.y); o[2] = f2bf(a.z); o[3] = f2bf(a.w);
  o[4] = f2bf(b.x); o[5] = f2bf(b.y); o[6] = f2bf(b.z); o[7] = f2bf(b.w);
  *(u16x8*)(out + i) = o;
}

// ---------------- RMSNorm (fp32 in) -> bf16 out ----------------
__global__ __launch_bounds__(256) void rmsnorm_cast(const float* __restrict__ x, const float* __restrict__ w,
                                                    u16* __restrict__ out) {
  const int row = blockIdx.x, tid = threadIdx.x;
  const float* xr = x + (size_t)row * 2048;
  float4 a = *(const float4*)(xr + tid * 8);
  float4 b = *(const float4*)(xr + tid * 8 + 4);
  float ss = a.x * a.x + a.y * a.y + a.z * a.z + a.w * a.w +
             b.x * b.x + b.y * b.y + b.z * b.z + b.w * b.w;
#pragma unroll
  for (int off = 32; off; off >>= 1) ss += __shfl_xor(ss, off);
  __shared__ float part[4];
  if ((tid & 63) == 0) part[tid >> 6] = ss;
  __syncthreads();
  float tot = part[0] + part[1] + part[2] + part[3];
  float r = rsqrtf(tot * (1.0f / 2048.0f) + 1e-5f);
  float4 wa = *(const float4*)(w + tid * 8);
  float4 wb = *(const float4*)(w + tid * 8 + 4);
  u16x8 o;
  o[0] = f2bf(a.x * r * wa.x); o[1] = f2bf(a.y * r * wa.y);
  o[2] = f2bf(a.z * r * wa.z); o[3] = f2bf(a.w * r * wa.w);
  o[4] = f2bf(b.x * r * wb.x); o[5] = f2bf(b.y * r * wb.y);
  o[6] = f2bf(b.z * r * wb.z); o[7] = f2bf(b.w * r * wb.w);
  *(u16x8*)(out + (size_t)row * 2048 + tid * 8) = o;
}

// ============ 256x256-tile, 8-wave, 8-phase NT GEMM (counted vmcnt) ============
// C[m,n] = dot(A[m,:], B[n,:]).  BK=32 per K-tile, 2 K-tiles per iteration.
// LDS 64KB: buf{0,1} x {A[256][32], B[256][32]} bf16, XOR-swizzled (T2).
// EPI 0: bf16 out (+batch z over B/out). EPI 1: fp32 out = acc + extra(fp32).
// EPI 2: bf16 out = extra(bf16)*silu(acc). EPI 3: fp32 partial at z (split-K).
template <int EPI>
__global__ __launch_bounds__(512) void gemm8(const u16* __restrict__ Ag, const u16* __restrict__ Bg,
                                             void* __restrict__ outp, const void* __restrict__ extra,
                                             int M, int N, int KC, int lda, int ldb, int koffStride,
                                             long long bStrideB, long long bStrideO) {
  __shared__ u16 lds[32768];  // 64 KiB
  const int z = blockIdx.z;
  const u16* Ap = Ag;
  const u16* Bp = Bg + (EPI == 0 ? (size_t)z * bStrideB : (size_t)0);
  const int koff = (EPI == 3) ? z * koffStride : 0;
  const int nbx = N >> 8;
  const int q8 = gridDim.x >> 3;  // grids are multiples of 8
  const int gid = blockIdx.x;
  const int lid = (gid & 7) * q8 + (gid >> 3);  // XCD-contiguous logical id (T1)
  const int by = lid / nbx, bx = lid % nbx;
  const int bm = by << 8, bn = bx << 8;
  const int tid = threadIdx.x;
  const int w = tid >> 6, l = tid & 63;
  const int wr = w >> 2, wc = w & 3;
  const int l16 = l & 15, l4 = l >> 4;
  const int NT2 = KC >> 6, NTT = KC >> 5;
  // staging lane constants: linear LDS dest, inverse-swizzled global source col
  const int srow = (w << 4) + (l >> 2);
  const int scolb = ((l & 3) << 4) ^ (((l >> 3) & 1) << 5) ^ (((l >> 4) & 1) << 4);
  char* ldsb = (char*)lds;

  auto STG = [&](const u16* src, int ldx, int rowBase, int kt, int ldsOffU16) {
    const char* g = (const char*)src + ((size_t)(rowBase + srow) * ldx + kt) * 2 + scolb;
    gload_lds16(g, ldsb + ldsOffU16 * 2 + (w << 10));
  };

  f32x4 acc[8][4] = {};
  u16x8 a[4], b[4];

  auto LDA4 = [&](int bufU16, int mh) {
#pragma unroll
    for (int j = 0; j < 4; ++j) {
      int row = wr * 128 + mh * 64 + j * 16 + l16;
      int off = (row << 5) + (l4 << 3);
      off ^= (((row >> 1) & 1) << 4) | (((row >> 2) & 1) << 3);
      a[j] = *(const u16x8*)(lds + bufU16 + off);
    }
  };
  auto LDB2 = [&](int bufU16, int nh) {
#pragma unroll
    for (int j = 0; j < 2; ++j) {
      int row = wc * 64 + nh * 32 + j * 16 + l16;
      int off = (row << 5) + (l4 << 3);
      off ^= (((row >> 1) & 1) << 4) | (((row >> 2) & 1) << 3);
      b[nh * 2 + j] = *(const u16x8*)(lds + bufU16 + 8192 + off);
    }
  };
  auto MM = [&](int mh, int nh) {
    __builtin_amdgcn_s_setprio(1);
#pragma unroll
    for (int mt = 0; mt < 4; ++mt)
#pragma unroll
      for (int nt = 0; nt < 2; ++nt)
        acc[mh * 4 + mt][nh * 2 + nt] = mfma16(a[mt], b[nh * 2 + nt], acc[mh * 4 + mt][nh * 2 + nt]);
    __builtin_amdgcn_s_setprio(0);
  };

  // Prologue: tile0 (A0,A1,B0,B1 -> buf0), tile1 (A0,A1 -> buf1)
  STG(Ap, lda, bm, koff, 0);
  STG(Ap, lda, bm + 128, koff, 4096);
  STG(Bp, ldb, bn, koff, 8192);
  STG(Bp, ldb, bn + 128, koff, 12288);
  STG(Ap, lda, bm, koff + 32, 16384);
  STG(Ap, lda, bm + 128, koff + 32, 20480);
  asm volatile("s_waitcnt vmcnt(2)" ::: "memory");
  __builtin_amdgcn_sched_barrier(0);
  __builtin_amdgcn_s_barrier();

  for (int it = 0; it < NT2; ++it) {
    const int t1 = 2 * it + 1, t2 = 2 * it + 2, t3 = 2 * it + 3;
    const int k1 = koff + (t1 < NTT ? t1 * 32 : 0);
    const int k2 = koff + (t2 < NTT ? t2 * 32 : 0);
    const int k3 = koff + (t3 < NTT ? t3 * 32 : 0);
    // ph1: read buf0 A(mh0)+B(nh0); stage t1.B0 -> buf1
    LDA4(0, 0); LDB2(0, 0);
    STG(Bp, ldb, bn, k1, 24576);
    __builtin_amdgcn_s_barrier();
    MM(0, 0);
    __builtin_amdgcn_s_barrier();
    // ph2: read buf0 B(nh1); stage t1.B1
    LDB2(0, 1);
    STG(Bp, ldb, bn + 128, k1, 28672);
    __builtin_amdgcn_s_barrier();
    MM(0, 1);
    __builtin_amdgcn_s_barrier();
    // ph3: read buf0 A(mh1)
    LDA4(0, 1);
    __builtin_amdgcn_s_barrier();
    MM(1, 0);
    __builtin_amdgcn_s_barrier();
    // ph4: stage t2.A0,A1 -> buf0; counted vmcnt
    STG(Ap, lda, bm, k2, 0);
    STG(Ap, lda, bm + 128, k2, 4096);
    asm volatile("s_waitcnt vmcnt(2)" ::: "memory");
    __builtin_amdgcn_sched_barrier(0);
    __builtin_amdgcn_s_barrier();
    MM(1, 1);
    __builtin_amdgcn_s_barrier();
    // ph5: read buf1 A(mh0)+B(nh0); stage t2.B0 -> buf0
    LDA4(16384, 0); LDB2(16384, 0);
    STG(Bp, ldb, bn, k2, 8192);
    __builtin_amdgcn_s_barrier();
    MM(0, 0);
    __builtin_amdgcn_s_barrier();
    // ph6: read buf1 B(nh1); stage t2.B1
    LDB2(16384, 1);
    STG(Bp, ldb, bn + 128, k2, 12288);
    __builtin_amdgcn_s_barrier();
    MM(0, 1);
    __builtin_amdgcn_s_barrier();
    // ph7: read buf1 A(mh1)
    LDA4(16384, 1);
    __builtin_amdgcn_s_barrier();
    MM(1, 0);
    __builtin_amdgcn_s_barrier();
    // ph8: stage t3.A0,A1 -> buf1; counted vmcnt
    STG(Ap, lda, bm, k3, 16384);
    STG(Ap, lda, bm + 128, k3, 20480);
    asm volatile("s_waitcnt vmcnt(2)" ::: "memory");
    __builtin_amdgcn_sched_barrier(0);
    __builtin_amdgcn_s_barrier();
    MM(1, 1);
    __builtin_amdgcn_s_barrier();
  }

#pragma unroll
  for (int i = 0; i < 8; ++i)
#pragma unroll
    for (int j = 0; j < 4; ++j)
#pragma unroll
      for (int r = 0; r < 4; ++r) {
        const int row = bm + wr * 128 + i * 16 + l4 * 4 + r;
        const int col = bn + wc * 64 + j * 16 + l16;
        const size_t idx = (size_t)row * N + col;
        float v = acc[i][j][r];
        if (EPI == 0) {
          ((u16*)outp)[(size_t)z * bStrideO + idx] = f2bf(v);
        } else if (EPI == 1) {
          ((float*)outp)[idx] = v + ((const float*)extra)[idx];
        } else if (EPI == 2) {
          float g = bf2f(((const u16*)extra)[idx]);
          float sig = 1.0f / (1.0f + __expf(-v));
          ((u16*)outp)[idx] = f2bf(g * v * sig);
        } else {
          ((float*)outp)[(size_t)z * M * N + idx] = v;
        }
      }
}

// ---------------- split-K reduce: out = p0+p1+p2+p3 + res ----------------
__global__ __launch_bounds__(256) void reduce4(const float* __restrict__ p, const float* __restrict__ res,
                                               float* __restrict__ out, size_t n) {
  size_t i = ((size_t)blockIdx.x * 256 + threadIdx.x) * 4;
  float4 a = *(const float4*)(p + i);
  float4 b = *(const float4*)(p + n + i);
  float4 c = *(const float4*)(p + 2 * n + i);
  float4 d = *(const float4*)(p + 3 * n + i);
  float4 r = *(const float4*)(res + i);
  float4 o;
  o.x = a.x + b.x + c.x + d.x + r.x;
  o.y = a.y + b.y + c.y + d.y + r.y;
  o.z = a.z + b.z + c.z + d.z + r.z;
  o.w = a.w + b.w + c.w + d.w + r.w;
  *(float4*)(out + i) = o;
}

// ---------------- RoPE ----------------
__global__ __launch_bounds__(256) void rope_table(float2* __restrict__ tab) {
  int idx = blockIdx.x * 256 + threadIdx.x;  // S*32 = 65536
  int pos = idx >> 5, i = idx & 31;
  float inv = __expf(-(float)(2 * i) * (9.210340371976184f / 64.0f));
  float a = (float)pos * inv;
  float s, c;
  __sincosf(a, &s, &c);
  tab[idx] = make_float2(c, s);
}

__global__ __launch_bounds__(256) void rope_apply(u16* __restrict__ q, u16* __restrict__ k,
                                                  const float2* __restrict__ tab) {
  int idx = blockIdx.x * 256 + threadIdx.x;  // S*H*32 = 2M
  int i = idx & 31;
  int hh = (idx >> 5) & 31;
  int pos = idx >> 10;
  float2 cs = tab[(pos << 5) + i];
  size_t base = (size_t)pos * 2048 + hh * 64 + i;
  float a0 = bf2f(q[base]), a1 = bf2f(q[base + 32]);
  q[base] = f2bf(a0 * cs.x - a1 * cs.y);
  q[base + 32] = f2bf(a1 * cs.x + a0 * cs.y);
  float b0 = bf2f(k[base]), b1 = bf2f(k[base + 32]);
  k[base] = f2bf(b0 * cs.x - b1 * cs.y);
  k[base + 32] = f2bf(b1 * cs.x + b0 * cs.y);
}

// ---------------- V transpose: v[S][D] -> vT[h][d][S] ----------------
__global__ __launch_bounds__(256) void transpose_v(const u16* __restrict__ v, u16* __restrict__ vt) {
  __shared__ u16 t[64][72];
  const int t0 = blockIdx.x * 64, h = blockIdx.y, tid = threadIdx.x;
  {
    const int r = tid >> 3, c8 = (tid & 7) * 8;
#pragma unroll
    for (int j = 0; j < 2; ++j) {
      u16x8 val = *(const u16x8*)(v + (size_t)(t0 + r + 32 * j) * 2048 + h * 64 + c8);
      *(u16x8*)&t[r + 32 * j][c8] = val;
    }
  }
  __syncthreads();
  const int d = tid >> 2, q = (tid & 3) * 16;
  u16x8 lo, hi;
#pragma unroll
  for (int e = 0; e < 8; ++e) lo[e] = t[q + e][d];
#pragma unroll
  for (int e = 0; e < 8; ++e) hi[e] = t[q + 8 + e][d];
  *(u16x8*)(vt + (size_t)(h * 64 + d) * 2048 + t0 + q) = lo;
  *(u16x8*)(vt + (size_t)(h * 64 + d) * 2048 + t0 + q + 8) = hi;
}

// ---------------- Flash attention ----------------
__global__ __launch_bounds__(256) void flash_attn(const u16* __restrict__ qb, const u16* __restrict__ kb,
                                                  const u16* __restrict__ vt, u16* __restrict__ ob) {
  const int h = blockIdx.y;
  const int q0 = blockIdx.x * 128;
  const int w = threadIdx.x >> 6, l = threadIdx.x & 63;
  const int l16 = l & 15, l4 = l >> 4;
  __shared__ u16 P[4][32][72];
  u16x8 qf[2][2];
#pragma unroll
  for (int rt = 0; rt < 2; ++rt)
#pragma unroll
    for (int kh = 0; kh < 2; ++kh)
      qf[rt][kh] = *(const u16x8*)(qb + (size_t)(q0 + w * 32 + rt * 16 + l16) * 2048 + h * 64 + kh * 32 + l4 * 8);
  float mrun[2][4], lrun[2][4];
  f32x4 oacc[2][4] = {};
#pragma unroll
  for (int rt = 0; rt < 2; ++rt)
#pragma unroll
    for (int r = 0; r < 4; ++r) { mrun[rt][r] = -1e30f; lrun[rt][r] = 0.f; }

  for (int t0 = 0; t0 < 2048; t0 += 64) {
    u16x8 kf[4][2];
#pragma unroll
    for (int tt = 0; tt < 4; ++tt)
#pragma unroll
      for (int kh = 0; kh < 2; ++kh)
        kf[tt][kh] = *(const u16x8*)(kb + (size_t)(t0 + tt * 16 + l16) * 2048 + h * 64 + kh * 32 + l4 * 8);
    f32x4 sacc[2][4] = {};
#pragma unroll
    for (int kh = 0; kh < 2; ++kh)
#pragma unroll
      for (int rt = 0; rt < 2; ++rt)
#pragma unroll
        for (int tt = 0; tt < 4; ++tt)
          sacc[rt][tt] = mfma16(qf[rt][kh], kf[tt][kh], sacc[rt][tt]);
    float sf[2][4];
#pragma unroll
    for (int rt = 0; rt < 2; ++rt)
#pragma unroll
      for (int r = 0; r < 4; ++r) {
        float v0 = sacc[rt][0][r] * 0.125f;
        float v1 = sacc[rt][1][r] * 0.125f;
        float v2 = sacc[rt][2][r] * 0.125f;
        float v3 = sacc[rt][3][r] * 0.125f;
        float mx = fmaxf(fmaxf(v0, v1), fmaxf(v2, v3));
        mx = fmaxf(mx, __shfl_xor(mx, 1));
        mx = fmaxf(mx, __shfl_xor(mx, 2));
        mx = fmaxf(mx, __shfl_xor(mx, 4));
        mx = fmaxf(mx, __shfl_xor(mx, 8));
        float mnew = fmaxf(mrun[rt][r], mx);
        float sfac = __expf(mrun[rt][r] - mnew);
        float p0 = __expf(v0 - mnew), p1 = __expf(v1 - mnew);
        float p2 = __expf(v2 - mnew), p3 = __expf(v3 - mnew);
        const int pr = rt * 16 + l4 * 4 + r;
        P[w][pr][l16] = f2bf(p0);
        P[w][pr][16 + l16] = f2bf(p1);
        P[w][pr][32 + l16] = f2bf(p2);
        P[w][pr][48 + l16] = f2bf(p3);
        float ps = p0 + p1 + p2 + p3;
        ps += __shfl_xor(ps, 1);
        ps += __shfl_xor(ps, 2);
        ps += __shfl_xor(ps, 4);
        ps += __shfl_xor(ps, 8);
        lrun[rt][r] = lrun[rt][r] * sfac + ps;
        mrun[rt][r] = mnew;
        sf[rt][r] = sfac;
      }
#pragma unroll
    for (int rt = 0; rt < 2; ++rt)
#pragma unroll
      for (int nt = 0; nt < 4; ++nt)
#pragma unroll
        for (int r = 0; r < 4; ++r)
          oacc[rt][nt][r] *= sf[rt][r];
#pragma unroll
    for (int ks = 0; ks < 2; ++ks) {
      u16x8 pf[2];
#pragma unroll
      for (int rt = 0; rt < 2; ++rt)
        pf[rt] = *(const u16x8*)&P[w][rt * 16 + l16][ks * 32 + l4 * 8];
#pragma unroll
      for (int nt = 0; nt < 4; ++nt) {
        u16x8 vf = *(const u16x8*)(vt + (size_t)(h * 64 + nt * 16 + l16) * 2048 + t0 + ks * 32 + l4 * 8);
#pragma unroll
        for (int rt = 0; rt < 2; ++rt)
          oacc[rt][nt] = mfma16(pf[rt], vf, oacc[rt][nt]);
      }
    }
  }
#pragma unroll
  for (int rt = 0; rt < 2; ++rt)
#pragma unroll
    for (int r = 0; r < 4; ++r) {
      float inv = 1.0f / lrun[rt][r];
#pragma unroll
      for (int nt = 0; nt < 4; ++nt)
        ob[(size_t)(q0 + w * 32 + rt * 16 + l4 * 4 + r) * 2048 + h * 64 + nt * 16 + l16] =
            f2bf(oacc[rt][nt][r] * inv);
    }
}

extern "C" void kernel_launch(void* const* d_in, const int* in_sizes, int n_in,
                              void* d_out, int out_size, void* d_ws, size_t ws_size,
                              hipStream_t stream) {
  const float* x    = (const float*)d_in[0];
  const float* w_in = (const float*)d_in[1];
  const float* wq   = (const float*)d_in[2];
  const float* wk   = (const float*)d_in[3];
  const float* wv   = (const float*)d_in[4];
  const float* wo   = (const float*)d_in[5];
  const float* w_pn = (const float*)d_in[6];
  const float* wg   = (const float*)d_in[7];
  const float* wu   = (const float*)d_in[8];
  const float* wd   = (const float*)d_in[9];
  float* out = (float*)d_out;
  char* ws = (char*)d_ws;
  const size_t MB = 1ull << 20;
  const int S = 2048, D = 2048, FF = 8192;

  u16* W_QKV = (u16*)(ws);               // 24 MB
  u16* W_O   = (u16*)(ws + 24 * MB);     // 8 MB
  u16* W_G   = (u16*)(ws + 32 * MB);     // 32 MB
  u16* W_U   = (u16*)(ws + 64 * MB);     // 32 MB
  u16* W_D   = (u16*)(ws + 96 * MB);     // 32 MB
  u16* HB    = (u16*)(ws + 128 * MB);    // 8 MB
  u16* QKVB  = (u16*)(ws + 136 * MB);    // 24 MB (q,k,v)
  u16* VT    = (u16*)(ws + 160 * MB);    // 8 MB
  u16* ATTNB = (u16*)(ws + 168 * MB);    // 8 MB
  float* X1  = (float*)(ws + 176 * MB);  // 16 MB
  u16* H2B   = (u16*)(ws + 192 * MB);    // 8 MB
  float2* RT = (float2*)(ws + 200 * MB); // 0.5 MB
  u16* GATEB = (u16*)(ws);               // 32 MB, overlays W_QKV+W_O (dead after O-proj)
  u16* PRODB = (u16*)(ws + 136 * MB);    // 32 MB, overlays QKVB+VT (dead after attention)
  float* DP  = (float*)(ws);             // 64 MB down-proj partials, overlays GATEB/W_G (dead by then)
  float* OP  = (float*)(ws + 208 * MB);  // 64 MB O-proj partials (only if ws permits)
  const bool splitO = ws_size >= 272 * MB;

  rope_table<<<65536 / 256, 256, 0, stream>>>(RT);
  cast_w<<<(D * D) / 2048, 256, 0, stream>>>(wq, W_QKV);
  cast_w<<<(D * D) / 2048, 256, 0, stream>>>(wk, W_QKV + (size_t)D * D);
  cast_w<<<(D * D) / 2048, 256, 0, stream>>>(wv, W_QKV + 2 * (size_t)D * D);
  cast_w<<<(D * D) / 2048, 256, 0, stream>>>(wo, W_O);
  cast_w<<<(FF * D) / 2048, 256, 0, stream>>>(wg, W_G);
  cast_w<<<(FF * D) / 2048, 256, 0, stream>>>(wu, W_U);
  cast_w<<<(FF * D) / 2048, 256, 0, stream>>>(wd, W_D);
  rmsnorm_cast<<<S, 256, 0, stream>>>(x, w_in, HB);
  // QKV: batched over z (B slabs), bf16 out
  gemm8<0><<<dim3(64, 1, 3), 512, 0, stream>>>(HB, W_QKV, QKVB, nullptr, S, D, D, D, D, 0,
                                               (long long)D * D, (long long)S * D);
  rope_apply<<<(S * 32 * 32) / 256, 256, 0, stream>>>(QKVB, QKVB + (size_t)S * D, RT);
  transpose_v<<<dim3(S / 64, 32), 256, 0, stream>>>(QKVB + 2 * (size_t)S * D, VT);
  flash_attn<<<dim3(S / 128, 32), 256, 0, stream>>>(QKVB, QKVB + (size_t)S * D, VT, ATTNB);
  // O-proj (+residual x) -> X1 fp32
  if (splitO) {
    gemm8<3><<<dim3(64, 1, 4), 512, 0, stream>>>(ATTNB, W_O, OP, nullptr, S, D, 512, D, D, 512, 0, 0);
    reduce4<<<(S * D) / 1024, 256, 0, stream>>>(OP, x, X1, (size_t)S * D);
  } else {
    gemm8<1><<<dim3(64, 1, 1), 512, 0, stream>>>(ATTNB, W_O, X1, x, S, D, D, D, D, 0, 0, 0);
  }
  rmsnorm_cast<<<S, 256, 0, stream>>>(X1, w_pn, H2B);
  gemm8<0><<<dim3(256, 1, 1), 512, 0, stream>>>(H2B, W_G, GATEB, nullptr, S, FF, D, D, D, 0, 0, 0);
  gemm8<2><<<dim3(256, 1, 1), 512, 0, stream>>>(H2B, W_U, PRODB, GATEB, S, FF, D, D, D, 0, 0, 0);
  // down-proj split-K x4 -> DP partials, then +X1 residual -> out
  gemm8<3><<<dim3(64, 1, 4), 512, 0, stream>>>(PRODB, W_D, DP, nullptr, S, D, 2048, FF, FF, 2048, 0, 0);
  reduce4<<<(S * D) / 1024, 256, 0, stream>>>(DP, X1, out, (size_t)S * D);
  (void)in_sizes; (void)n_in; (void)out_size;
}